// Round 6
// baseline (546.308 us; speedup 1.0000x reference)
//
#include <hip/hip_runtime.h>

// LSTM B=8192,T=256,I=1,H=50 via MFMA -- BARRIER-FREE single-wave recurrence.
// Each 64-thread block (1 wave) owns 16 batches for all 256 steps and computes
// ALL 13 row-tiles itself: D[208x16] = W[208x64] x h[64x16], rows=unit*4+gate
// (50 real units + x-col k=50 + bias-col k=51), cols=batches. C/D layout puts
// the 4 gates of (batch=lane&15, unit=4T+quad) in one lane's 4 acc regs ->
// activations in-register. h round-trips LDS as bf16 hi+lo planes; same-wave
// DS ordering (lgkmcnt) replaces __syncthreads -> zero barriers in the t-loop.
// W fragments: 13 tiles x 16 VGPR = 208 regs, launch_bounds(64,1) allows it.
// 512 blocks -> 2 independent waves/CU on separate SIMDs.
// Numerics = R4 (3-product bf16 hi/lo ~ fp32; verified absmax 9.8e-4).

#define NTH 64
#define TST 256
#define MB 16
#define NBLK 512
#define HR 72            // h row stride in shorts (16B-aligned b128 frag reads)

typedef __attribute__((ext_vector_type(8))) short short8;
typedef __attribute__((ext_vector_type(4))) float float4v;

__device__ __forceinline__ unsigned short bfhi(float v) {
    return (unsigned short)(__float_as_uint(v) >> 16);  // truncate; lo catches rest
}
__device__ __forceinline__ float bfup(unsigned short u) {
    return __uint_as_float(((unsigned int)u) << 16);
}
__device__ __forceinline__ float sigm(float v) {
    return __builtin_amdgcn_rcpf(1.0f + __expf(-v));
}
__device__ __forceinline__ float tanh_fast(float v) {
    float e = __expf(2.0f * v);
    return 1.0f - 2.0f * __builtin_amdgcn_rcpf(e + 1.0f);
}

__global__ __launch_bounds__(NTH, 1) void lstm_wave(
    const float* __restrict__ x,      // [8192][256]
    const float* __restrict__ W_ih,   // [200]
    const float* __restrict__ W_hh,   // [200][50]
    const float* __restrict__ b_ih,   // [200]
    const float* __restrict__ b_hh,   // [200]
    const float* __restrict__ W_lin,  // [50]
    const float* __restrict__ b_lin,  // [1]
    float* __restrict__ out)          // [8192]
{
    __shared__ __align__(16) unsigned short Hhi[MB * HR];  // single buffer
    __shared__ __align__(16) unsigned short Hlo[MB * HR];

    const int tid  = threadIdx.x;          // 0..63, one wave
    const int lrow = tid & 15;             // batch-in-block / D col
    const int quad = tid >> 4;
    const int bbase = (int)blockIdx.x * MB;

    // ---- W-operand fragments, tiles T=0..12 (208 VGPR, one-time L2 reads).
    // Row gr=T*16+lrow -> unit j=gr>>2, gate g=gr&3, W row = g*50+j.
    // k = q2*32 + quad*8 + i; k=50 -> W_ih, k=51 -> bias; pad rows (j>=50) zero.
    short8 wh[13][2], wl[13][2];
    #pragma unroll
    for (int T = 0; T < 13; ++T) {
        const int gr = T * 16 + lrow;
        const int j  = gr >> 2, g = gr & 3;
        const int row = g * 50 + j;        // only dereferenced when j < 50
        #pragma unroll
        for (int q2 = 0; q2 < 2; ++q2) {
            short8 h8, l8;
            #pragma unroll
            for (int i = 0; i < 8; ++i) {
                const int k = q2 * 32 + quad * 8 + i;
                float V = 0.0f;
                if (j < 50) {
                    if (k < 50)       V = W_hh[row * 50 + k];
                    else if (k == 50) V = W_ih[row];
                    else if (k == 51) V = b_ih[row] + b_hh[row];
                }
                unsigned short hb = bfhi(V);
                h8[i] = (short)hb;
                l8[i] = (short)bfhi(V - bfup(hb));
            }
            wh[T][q2] = h8;
            wl[T][q2] = l8;
        }
    }

    // ---- init h planes: zeros; k=50 <- x(b,0); k=51 <- 1.0 (never rewritten)
    for (int i = tid; i < MB * HR / 2; i += NTH) {
        ((unsigned int*)Hhi)[i] = 0u;
        ((unsigned int*)Hlo)[i] = 0u;
    }
    __syncthreads();                       // trivial for 1 wave; ordering safety
    if (tid < MB) {
        float xv = x[(bbase + tid) * TST + 0];
        unsigned short xh = bfhi(xv);
        Hhi[tid * HR + 50] = xh;
        Hlo[tid * HR + 50] = bfhi(xv - bfup(xh));
        Hhi[tid * HR + 51] = 0x3F80;       // bf16(1.0)
    }
    __syncthreads();

    float cst[13];
    #pragma unroll
    for (int T = 0; T < 13; ++T) cst[T] = 0.f;

    const float* xb = &x[(bbase + lrow) * TST];   // per-lane x row
    const int ha = lrow * HR + quad * 8;

    for (int t = 0; t < TST; ++t) {
        const int tn = (t < TST - 1) ? (t + 1) : (TST - 1);
        const float xnext = xb[tn];        // early issue; L1-hot (64B/16 steps)

        // ---- h fragments (4 x ds_read_b128); RAW vs prev step's writes is
        // same-wave in-order DS + compiler lgkmcnt.
        const short8 bh0 = *(const short8*)&Hhi[ha];
        const short8 bh1 = *(const short8*)&Hhi[ha + 32];
        const short8 bl0 = *(const short8*)&Hlo[ha];
        const short8 bl1 = *(const short8*)&Hlo[ha + 32];

        #pragma unroll
        for (int T = 0; T < 13; ++T) {
            float4v a4 = {0.f, 0.f, 0.f, 0.f};
            a4 = __builtin_amdgcn_mfma_f32_16x16x32_bf16(wh[T][0], bh0, a4, 0, 0, 0);
            a4 = __builtin_amdgcn_mfma_f32_16x16x32_bf16(wh[T][1], bh1, a4, 0, 0, 0);
            a4 = __builtin_amdgcn_mfma_f32_16x16x32_bf16(wl[T][0], bh0, a4, 0, 0, 0);
            a4 = __builtin_amdgcn_mfma_f32_16x16x32_bf16(wl[T][1], bh1, a4, 0, 0, 0);
            a4 = __builtin_amdgcn_mfma_f32_16x16x32_bf16(wh[T][0], bl0, a4, 0, 0, 0);
            a4 = __builtin_amdgcn_mfma_f32_16x16x32_bf16(wh[T][1], bl1, a4, 0, 0, 0);

            // lane = (batch lrow, unit 4T+quad); regs = gates i,f,g,o
            float i_ = sigm(a4[0]);
            float f_ = sigm(a4[1]);
            float g_ = tanh_fast(a4[2]);
            float o_ = sigm(a4[3]);
            float cn = f_ * cst[T] + i_ * g_;
            cst[T] = cn;
            float hn = o_ * tanh_fast(cn);

            bool wr = true;
            if (T == 12) {                 // units 48..51: quad2 = x slot, quad3 = 1.0
                if (quad == 2)      hn = xnext;
                else if (quad == 3) wr = false;
            }
            if (wr) {
                const int j = T * 4 + quad;
                unsigned short hh = bfhi(hn);
                Hhi[lrow * HR + j] = hh;
                Hlo[lrow * HR + j] = bfhi(hn - bfup(hh));
            }
        }
        // no barrier: next iteration's ds_reads are ordered after these writes
        // within the wave by the DS pipe + lgkmcnt.
    }

    __syncthreads();
    // ---- epilogue: out[b] = b_lin + sum_k h[b][k] * W_lin[k]
    if (tid < MB) {
        float s = b_lin[0];
        #pragma unroll 10
        for (int k = 0; k < 50; ++k) {
            float hk = bfup(Hhi[tid * HR + k]) + bfup(Hlo[tid * HR + k]);
            s += hk * W_lin[k];
        }
        out[bbase + tid] = s;
    }
}

extern "C" void kernel_launch(void* const* d_in, const int* in_sizes, int n_in,
                              void* d_out, int out_size, void* d_ws, size_t ws_size,
                              hipStream_t stream) {
    const float* x     = (const float*)d_in[0];
    const float* W_ih  = (const float*)d_in[1];
    const float* W_hh  = (const float*)d_in[2];
    const float* b_ih  = (const float*)d_in[3];
    const float* b_hh  = (const float*)d_in[4];
    const float* W_lin = (const float*)d_in[5];
    const float* b_lin = (const float*)d_in[6];
    float* out = (float*)d_out;

    lstm_wave<<<dim3(NBLK), dim3(NTH), 0, stream>>>(
        x, W_ih, W_hh, b_ih, b_hh, W_lin, b_lin, out);
}

// Round 7
// 281.972 us; speedup vs baseline: 1.9375x; 1.9375x over previous
//
#include <hip/hip_runtime.h>

// LSTM B=8192,T=256,I=1,H=50 via MFMA, operand-swapped, MAX-TLP split.
// Per block: 16 batches, 8 waves (NTH=512), 512 blocks -> 2 blocks/CU =
// 16 waves/CU (4/SIMD). Per step: D[208x16] = W[208x64] x h[64x16],
// rows = unit*4+gate (50 real units + x-col k=50 + bias-col k=51),
// cols = batches. Wave wv owns tiles T = wv and wv+8 (T<=12): waves 0-4
// do 2 tiles, 5-7 one tile. C/D layout puts the 4 gates of (batch=lane&15,
// unit=4T+quad) in one lane's 4 acc regs -> activations in-register.
// h double-buffered in LDS as bf16 hi+lo planes, ONE barrier/step.
// Latency-bound kernel: R4-R6 showed wall ~ 1/waves-per-CU; this doubles
// waves vs R4 by halving per-wave tile share (work total invariant).
// Numerics = R3/R4 (3-product bf16 hi/lo ~ fp32; verified absmax 9.8e-4).

#define NTH 512
#define TST 256
#define MB 16
#define NBLK 512
#define HR 72            // h row stride in shorts (16B-aligned b128 frag reads)
#define HSZ (MB * HR)    // 1152 shorts per buffer

typedef __attribute__((ext_vector_type(8))) short short8;
typedef __attribute__((ext_vector_type(4))) float float4v;

__device__ __forceinline__ unsigned short bfhi(float v) {
    return (unsigned short)(__float_as_uint(v) >> 16);  // truncate; lo catches rest
}
__device__ __forceinline__ float bfup(unsigned short u) {
    return __uint_as_float(((unsigned int)u) << 16);
}
__device__ __forceinline__ float sigm(float v) {
    return __builtin_amdgcn_rcpf(1.0f + __expf(-v));
}
__device__ __forceinline__ float tanh_fast(float v) {
    float e = __expf(2.0f * v);
    return 1.0f - 2.0f * __builtin_amdgcn_rcpf(e + 1.0f);
}

__global__ __launch_bounds__(NTH, 4) void lstm_mfma(
    const float* __restrict__ x,      // [8192][256]
    const float* __restrict__ W_ih,   // [200]
    const float* __restrict__ W_hh,   // [200][50]
    const float* __restrict__ b_ih,   // [200]
    const float* __restrict__ b_hh,   // [200]
    const float* __restrict__ W_lin,  // [50]
    const float* __restrict__ b_lin,  // [1]
    float* __restrict__ out)          // [8192]
{
    __shared__ __align__(16) unsigned short Hhi[2 * HSZ];  // [buf][b*HR + k]
    __shared__ __align__(16) unsigned short Hlo[2 * HSZ];

    const int tid  = threadIdx.x;
    const int wv   = tid >> 6;      // 0..7
    const int ln   = tid & 63;
    const int lrow = ln & 15;       // batch-in-block / D col
    const int quad = ln >> 4;
    const int bbase = (int)blockIdx.x * MB;

    // ---- W-operand fragments, slots s=0,1 -> tile T = wv + 8s (valid T<=12).
    // Row gr=T*16+lrow -> unit j=gr>>2, gate g=gr&3, W row = g*50+j.
    // k = q2*32 + quad*8 + i; k=50 -> W_ih, k=51 -> bias; pad rows (j>=50) zero.
    short8 wh[2][2], wl[2][2];
    #pragma unroll
    for (int s = 0; s < 2; ++s) {
        const int T  = wv + 8 * s;
        const int gr = T * 16 + lrow;
        const int j  = gr >> 2, g = gr & 3;
        const int row = g * 50 + j;   // only dereferenced when valid && j<50
        #pragma unroll
        for (int q2 = 0; q2 < 2; ++q2) {
            short8 h8, l8;
            #pragma unroll
            for (int i = 0; i < 8; ++i) {
                const int k = q2 * 32 + quad * 8 + i;
                float V = 0.0f;
                if (T <= 12 && j < 50) {
                    if (k < 50)       V = W_hh[row * 50 + k];
                    else if (k == 50) V = W_ih[row];
                    else if (k == 51) V = b_ih[row] + b_hh[row];
                }
                unsigned short hb = bfhi(V);
                h8[i] = (short)hb;
                l8[i] = (short)bfhi(V - bfup(hb));
            }
            wh[s][q2] = h8;
            wl[s][q2] = l8;
        }
    }

    // ---- zero h planes; k=50 <- x(b,0) in buf0; k=51 <- 1.0 in BOTH bufs
    for (int i = tid; i < HSZ; i += NTH) {   // HSZ dwords per plane
        ((unsigned int*)Hhi)[i] = 0u;
        ((unsigned int*)Hlo)[i] = 0u;
    }
    __syncthreads();
    if (tid < MB) {
        float xv = x[(bbase + tid) * TST + 0];
        unsigned short xh = bfhi(xv);
        Hhi[tid * HR + 50] = xh;
        Hlo[tid * HR + 50] = bfhi(xv - bfup(xh));
        Hhi[tid * HR + 51] = 0x3F80;         // bf16(1.0), never rewritten
        Hhi[HSZ + tid * HR + 51] = 0x3F80;
    }
    __syncthreads();

    float cst[2] = {0.f, 0.f};
    const float* xb = &x[(bbase + lrow) * TST];   // per-lane x row (wave 4 uses)
    const int ha = lrow * HR + quad * 8;

    for (int t = 0; t < TST; ++t) {
        const int buf  = (t & 1) * HSZ;
        const int nbuf = HSZ - buf;

        // x(t+1) for the T=12 x-column (wave 4 only; wave-uniform branch,
        // 16 distinct addresses, L1-hot line for 16 consecutive steps)
        float xnext = 0.0f;
        if (wv == 4) {
            const int tn = (t < TST - 1) ? (t + 1) : (TST - 1);
            xnext = xb[tn];
        }

        // ---- h fragments (4 x ds_read_b128) from current buffer
        const short8 bh0 = *(const short8*)&Hhi[buf + ha];
        const short8 bh1 = *(const short8*)&Hhi[buf + ha + 32];
        const short8 bl0 = *(const short8*)&Hlo[buf + ha];
        const short8 bl1 = *(const short8*)&Hlo[buf + ha + 32];

        #pragma unroll
        for (int s = 0; s < 2; ++s) {
            const int T = wv + 8 * s;
            if (T > 12) break;               // waves 5-7: single tile
            float4v a4 = {0.f, 0.f, 0.f, 0.f};
            a4 = __builtin_amdgcn_mfma_f32_16x16x32_bf16(wh[s][0], bh0, a4, 0, 0, 0);
            a4 = __builtin_amdgcn_mfma_f32_16x16x32_bf16(wh[s][1], bh1, a4, 0, 0, 0);
            a4 = __builtin_amdgcn_mfma_f32_16x16x32_bf16(wl[s][0], bh0, a4, 0, 0, 0);
            a4 = __builtin_amdgcn_mfma_f32_16x16x32_bf16(wl[s][1], bh1, a4, 0, 0, 0);
            a4 = __builtin_amdgcn_mfma_f32_16x16x32_bf16(wh[s][0], bl0, a4, 0, 0, 0);
            a4 = __builtin_amdgcn_mfma_f32_16x16x32_bf16(wh[s][1], bl1, a4, 0, 0, 0);

            // lane = (batch lrow, unit 4T+quad); regs = gates i,f,g,o
            float i_ = sigm(a4[0]);
            float f_ = sigm(a4[1]);
            float g_ = tanh_fast(a4[2]);
            float o_ = sigm(a4[3]);
            float cn = f_ * cst[s] + i_ * g_;
            cst[s] = cn;
            float hn = o_ * tanh_fast(cn);

            bool wr = true;
            if (T == 12) {                   // units 48..51: quad2 = x slot, quad3 = 1.0
                if (quad == 2)      hn = xnext;
                else if (quad == 3) wr = false;
            }
            if (wr) {
                const int j = T * 4 + quad;
                unsigned short hh = bfhi(hn);
                Hhi[nbuf + lrow * HR + j] = hh;
                Hlo[nbuf + lrow * HR + j] = bfhi(hn - bfup(hh));
            }
        }
        __syncthreads();   // publish nbuf h for next step
    }

    // ---- epilogue: final h in buf 0 (t=255 wrote nbuf=0)
    if (tid < MB) {
        float s = b_lin[0];
        #pragma unroll 10
        for (int k = 0; k < 50; ++k) {
            float hk = bfup(Hhi[tid * HR + k]) + bfup(Hlo[tid * HR + k]);
            s += hk * W_lin[k];
        }
        out[bbase + tid] = s;
    }
}

extern "C" void kernel_launch(void* const* d_in, const int* in_sizes, int n_in,
                              void* d_out, int out_size, void* d_ws, size_t ws_size,
                              hipStream_t stream) {
    const float* x     = (const float*)d_in[0];
    const float* W_ih  = (const float*)d_in[1];
    const float* W_hh  = (const float*)d_in[2];
    const float* b_ih  = (const float*)d_in[3];
    const float* b_hh  = (const float*)d_in[4];
    const float* W_lin = (const float*)d_in[5];
    const float* b_lin = (const float*)d_in[6];
    float* out = (float*)d_out;

    lstm_mfma<<<dim3(NBLK), dim3(NTH), 0, stream>>>(
        x, W_ih, W_hh, b_ih, b_hh, W_lin, b_lin, out);
}

// Round 8
// 241.894 us; speedup vs baseline: 2.2585x; 1.1657x over previous
//
#include <hip/hip_runtime.h>

// LSTM B=8192,T=256,I=1,H=50 via MFMA, fp16 two-product + 13-wave split.
// Per block: 16 batches, 13 waves (NTH=832), wave wv owns tile T=wv.
// Per step: D[208x16] = W[208x64] x h[64x16]; rows = unit*4+gate
// (50 real units + x-col k=50 + bias-col k=51), cols = batches.
// C/D layout: lane (lrow=ln&15, quad=ln>>4) of wave T gets the 4 gates of
// (batch=lrow, unit=4T+quad) in its 4 acc regs -> activations in-register.
// Numerics: W pre-scaled (sigmoid rows by -log2e, g rows by +2log2e -> gates
// feed exp2 directly) and split hi/lo in fp16 (W ~exact); h stored as SINGLE
// fp16 plane (rel err 2^-11, random) -> 4 MFMA/tile, 2 frag reads, 1 write.
// h double-buffered, ONE barrier/step. 512 blocks x 13 waves = 26 waves/CU.

#define NTH 832
#define TST 256
#define MB 16
#define NBLK 512
#define HR 72            // h row stride in halfs (16B-aligned b128 frag reads)
#define HSZ (MB * HR)    // 1152 halfs per buffer

#define LOG2E 1.44269504088896f

typedef __attribute__((ext_vector_type(8))) _Float16 half8;
typedef __attribute__((ext_vector_type(4))) float float4v;

__device__ __forceinline__ float rcp_(float v)  { return __builtin_amdgcn_rcpf(v); }
__device__ __forceinline__ float exp2_(float v) { return __builtin_amdgcn_exp2f(v); }
__device__ __forceinline__ unsigned short f16bits(float v) {
    _Float16 h = (_Float16)v;                 // RNE
    return *(unsigned short*)&h;
}

__global__ __launch_bounds__(NTH, 7) void lstm_mfma(
    const float* __restrict__ x,      // [8192][256]
    const float* __restrict__ W_ih,   // [200]
    const float* __restrict__ W_hh,   // [200][50]
    const float* __restrict__ b_ih,   // [200]
    const float* __restrict__ b_hh,   // [200]
    const float* __restrict__ W_lin,  // [50]
    const float* __restrict__ b_lin,  // [1]
    float* __restrict__ out)          // [8192]
{
    __shared__ __align__(16) unsigned short Hh[2 * HSZ];   // fp16 h, double-buffered

    const int tid  = threadIdx.x;
    const int wv   = tid >> 6;      // 0..12 = tile T
    const int ln   = tid & 63;
    const int lrow = ln & 15;       // batch-in-block / A-row m / D col
    const int quad = ln >> 4;
    const int bbase = (int)blockIdx.x * MB;
    const int T = wv;

    // ---- W-operand fragments (one tile per wave; one-time L2 reads).
    // Row gr=T*16+lrow -> unit j=gr>>2, gate g=gr&3, W row = g*50+j.
    // k = q2*32 + quad*8 + i; k=50 -> W_ih, k=51 -> bias; pad rows (j>=50) zero.
    // Pre-scale: sigmoid rows (g!=2) by -log2e, g rows by +2log2e.
    half8 wh[2], wl[2];
    {
        const int gr = T * 16 + lrow;
        const int j  = gr >> 2, g = gr & 3;
        const int row = g * 50 + j;             // only dereferenced when j<50
        const float scl = (g == 2) ? (2.0f * LOG2E) : (-LOG2E);
        #pragma unroll
        for (int q2 = 0; q2 < 2; ++q2) {
            half8 h8, l8;
            #pragma unroll
            for (int i = 0; i < 8; ++i) {
                const int k = q2 * 32 + quad * 8 + i;
                float V = 0.0f;
                if (j < 50) {
                    if (k < 50)       V = W_hh[row * 50 + k];
                    else if (k == 50) V = W_ih[row];
                    else if (k == 51) V = b_ih[row] + b_hh[row];
                }
                V *= scl;
                _Float16 hi = (_Float16)V;
                h8[i] = hi;
                l8[i] = (_Float16)(V - (float)hi);
            }
            wh[q2] = h8;
            wl[q2] = l8;
        }
    }

    // ---- init h: zeros; k=50 <- fp16(x(b,0)) buf0; k=51 <- fp16(1.0) BOTH bufs
    for (int i = tid; i < HSZ; i += NTH)       // HSZ uints = 2*HSZ halfs (both bufs)
        ((unsigned int*)Hh)[i] = 0u;
    __syncthreads();
    if (tid < MB) {
        float xv = x[(bbase + tid) * TST + 0];
        Hh[tid * HR + 50] = f16bits(xv);
        Hh[tid * HR + 51] = 0x3C00;            // fp16(1.0), never rewritten
        Hh[HSZ + tid * HR + 51] = 0x3C00;
    }
    __syncthreads();

    float c = 0.0f;
    const float* xb = &x[(bbase + lrow) * TST];    // wave 12's x row
    const int ha = lrow * HR + quad * 8;
    const int jw = T * 4 + quad;                   // unit this lane writes

    for (int t = 0; t < TST; ++t) {
        const int buf  = (t & 1) * HSZ;
        const int nbuf = HSZ - buf;

        // x(t+1) for the k=50 column (wave 12 / quad 2; L1-hot line 16 steps)
        float xnext = 0.0f;
        if (wv == 12) {
            const int tn = (t < TST - 1) ? (t + 1) : (TST - 1);
            xnext = xb[tn];
        }

        // ---- h fragments (2 x ds_read_b128) from current buffer
        const half8 b0 = *(const half8*)&Hh[buf + ha];
        const half8 b1 = *(const half8*)&Hh[buf + ha + 32];

        float4v a4 = {0.f, 0.f, 0.f, 0.f};
        a4 = __builtin_amdgcn_mfma_f32_16x16x32_f16(wh[0], b0, a4, 0, 0, 0);
        a4 = __builtin_amdgcn_mfma_f32_16x16x32_f16(wh[1], b1, a4, 0, 0, 0);
        a4 = __builtin_amdgcn_mfma_f32_16x16x32_f16(wl[0], b0, a4, 0, 0, 0);
        a4 = __builtin_amdgcn_mfma_f32_16x16x32_f16(wl[1], b1, a4, 0, 0, 0);

        // gates pre-scaled: sigm = rcp(1+exp2(a)); tanh = 1-2*rcp(exp2(a)+1)
        float i_ = rcp_(1.0f + exp2_(a4[0]));
        float f_ = rcp_(1.0f + exp2_(a4[1]));
        float g_ = fmaf(-2.0f, rcp_(exp2_(a4[2]) + 1.0f), 1.0f);
        float o_ = rcp_(1.0f + exp2_(a4[3]));
        float cn = f_ * c + i_ * g_;
        c = cn;
        float th = fmaf(-2.0f, rcp_(exp2_(2.0f * LOG2E * cn) + 1.0f), 1.0f);
        float hn = o_ * th;

        bool wr = true;
        if (wv == 12) {                        // units 48..51: quad2 = x, quad3 = 1.0
            if (quad == 2)      hn = xnext;
            else if (quad == 3) wr = false;
        }
        if (wr)
            Hh[nbuf + lrow * HR + jw] = f16bits(hn);

        __syncthreads();                       // publish nbuf h for next step
    }

    // ---- epilogue: final h in buf 0 (t=255 wrote nbuf=0)
    if (tid < MB) {
        float s = b_lin[0];
        #pragma unroll 10
        for (int k = 0; k < 50; ++k) {
            float hk = (float)(*(const _Float16*)&Hh[tid * HR + k]);
            s += hk * W_lin[k];
        }
        out[bbase + tid] = s;
    }
}

extern "C" void kernel_launch(void* const* d_in, const int* in_sizes, int n_in,
                              void* d_out, int out_size, void* d_ws, size_t ws_size,
                              hipStream_t stream) {
    const float* x     = (const float*)d_in[0];
    const float* W_ih  = (const float*)d_in[1];
    const float* W_hh  = (const float*)d_in[2];
    const float* b_ih  = (const float*)d_in[3];
    const float* b_hh  = (const float*)d_in[4];
    const float* W_lin = (const float*)d_in[5];
    const float* b_lin = (const float*)d_in[6];
    float* out = (float*)d_out;

    lstm_mfma<<<dim3(NBLK), dim3(NTH), 0, stream>>>(
        x, W_ih, W_hh, b_ih, b_hh, W_lin, b_lin, out);
}

// Round 9
// 232.949 us; speedup vs baseline: 2.3452x; 1.0384x over previous
//
#include <hip/hip_runtime.h>

// LSTM B=8192,T=256,I=1,H=50 via MFMA, fp16 two-product, 13-wave split,
// R9: 2-step unrolled loop with immediate LDS offsets, hoisted addresses,
// persistent zero accumulator (MFMA D!=C) -- pure instruction diet vs R8.
// Per block: 16 batches, 13 waves (NTH=832), wave wv owns tile T=wv.
// Per step: D[208x16] = W[208x64] x h[64x16]; rows = unit*4+gate
// (50 real units + x-col k=50 + bias-col k=51), cols = batches.
// C/D layout: lane (lrow=ln&15, quad=ln>>4) of wave T gets the 4 gates of
// (batch=lrow, unit=4T+quad) in its 4 acc regs -> activations in-register.
// W pre-scaled (sigmoid rows by -log2e, g rows by +2log2e) so gates feed
// exp2 directly; W split hi/lo fp16 (~exact), h single fp16 plane.
// h double-buffered, ONE barrier/step. 512 blocks x 13 waves = 26 waves/CU.

#define NTH 832
#define TST 256
#define MB 16
#define NBLK 512
#define HR 72            // h row stride in halfs (16B-aligned b128 frag reads)
#define HSZ (MB * HR)    // 1152 halfs per buffer

#define LOG2E 1.44269504088896f

typedef __attribute__((ext_vector_type(8))) _Float16 half8;
typedef __attribute__((ext_vector_type(4))) float float4v;

__device__ __forceinline__ float rcp_(float v)  { return __builtin_amdgcn_rcpf(v); }
__device__ __forceinline__ float exp2_(float v) { return __builtin_amdgcn_exp2f(v); }
__device__ __forceinline__ unsigned short f16bits(float v) {
    _Float16 h = (_Float16)v;                 // RNE
    return *(unsigned short*)&h;
}

__global__ __launch_bounds__(NTH, 7) void lstm_mfma(
    const float* __restrict__ x,      // [8192][256]
    const float* __restrict__ W_ih,   // [200]
    const float* __restrict__ W_hh,   // [200][50]
    const float* __restrict__ b_ih,   // [200]
    const float* __restrict__ b_hh,   // [200]
    const float* __restrict__ W_lin,  // [50]
    const float* __restrict__ b_lin,  // [1]
    float* __restrict__ out)          // [8192]
{
    __shared__ __align__(16) unsigned short Hh[2 * HSZ];   // fp16 h, double-buffered

    const int tid  = threadIdx.x;
    const int wv   = tid >> 6;      // 0..12 = tile T
    const int ln   = tid & 63;
    const int lrow = ln & 15;       // batch-in-block / A-row m / D col
    const int quad = ln >> 4;
    const int bbase = (int)blockIdx.x * MB;
    const int T = wv;

    // ---- W-operand fragments (one tile per wave; one-time L2 reads).
    // Row gr=T*16+lrow -> unit j=gr>>2, gate g=gr&3, W row = g*50+j.
    // k = q2*32 + quad*8 + i; k=50 -> W_ih, k=51 -> bias; pad rows (j>=50) zero.
    // Pre-scale: sigmoid rows (g!=2) by -log2e, g rows by +2log2e.
    half8 wh[2], wl[2];
    {
        const int gr = T * 16 + lrow;
        const int j  = gr >> 2, g = gr & 3;
        const int row = g * 50 + j;             // only dereferenced when j<50
        const float scl = (g == 2) ? (2.0f * LOG2E) : (-LOG2E);
        #pragma unroll
        for (int q2 = 0; q2 < 2; ++q2) {
            half8 h8, l8;
            #pragma unroll
            for (int i = 0; i < 8; ++i) {
                const int k = q2 * 32 + quad * 8 + i;
                float V = 0.0f;
                if (j < 50) {
                    if (k < 50)       V = W_hh[row * 50 + k];
                    else if (k == 50) V = W_ih[row];
                    else if (k == 51) V = b_ih[row] + b_hh[row];
                }
                V *= scl;
                _Float16 hi = (_Float16)V;
                h8[i] = hi;
                l8[i] = (_Float16)(V - (float)hi);
            }
            wh[q2] = h8;
            wl[q2] = l8;
        }
    }

    // ---- init h: zeros; k=50 <- fp16(x(b,0)) buf0; k=51 <- fp16(1.0) BOTH bufs
    for (int i = tid; i < HSZ; i += NTH)       // HSZ uints = 2*HSZ halfs (both bufs)
        ((unsigned int*)Hh)[i] = 0u;
    __syncthreads();
    if (tid < MB) {
        float xv = x[(bbase + tid) * TST + 0];
        Hh[tid * HR + 50] = f16bits(xv);
        Hh[tid * HR + 51] = 0x3C00;            // fp16(1.0), never rewritten
        Hh[HSZ + tid * HR + 51] = 0x3C00;
    }
    __syncthreads();

    float c = 0.0f;
    const float* xb = &x[(bbase + lrow) * TST];            // wave 12's x row
    const unsigned short* Hr = &Hh[lrow * HR + quad * 8];  // read base (hoisted)
    unsigned short*       Hw = &Hh[lrow * HR + T * 4 + quad]; // write base (hoisted)
    const bool xlane   = (wv == 12) && (quad == 2);        // k=50 column owner
    const bool skiplan = (wv == 12) && (quad == 3);        // k=51 constant column
    const float4v z4 = {0.f, 0.f, 0.f, 0.f};               // persistent zero C operand

    // one LSTM step; roff/woff are compile-time after inlining -> immediate offsets
    auto step1 = [&](int roff, int woff, float xnext) {
        const half8 b0 = *(const half8*)(Hr + roff);
        const half8 b1 = *(const half8*)(Hr + roff + 32);

        float4v a4;
        a4 = __builtin_amdgcn_mfma_f32_16x16x32_f16(wh[0], b0, z4, 0, 0, 0);
        a4 = __builtin_amdgcn_mfma_f32_16x16x32_f16(wh[1], b1, a4, 0, 0, 0);
        a4 = __builtin_amdgcn_mfma_f32_16x16x32_f16(wl[0], b0, a4, 0, 0, 0);
        a4 = __builtin_amdgcn_mfma_f32_16x16x32_f16(wl[1], b1, a4, 0, 0, 0);

        // gates pre-scaled: sigm = rcp(1+exp2(a)); tanh = 1-2*rcp(exp2(a)+1)
        float i_ = rcp_(1.0f + exp2_(a4[0]));
        float f_ = rcp_(1.0f + exp2_(a4[1]));
        float g_ = fmaf(-2.0f, rcp_(exp2_(a4[2]) + 1.0f), 1.0f);
        float o_ = rcp_(1.0f + exp2_(a4[3]));
        float cn = f_ * c + i_ * g_;
        c = cn;
        float th = fmaf(-2.0f, rcp_(exp2_(2.0f * LOG2E * cn) + 1.0f), 1.0f);
        float hn = o_ * th;

        if (xlane) hn = xnext;                 // k=50 column <- x(t+1)
        if (!skiplan)
            Hw[woff] = f16bits(hn);
        __syncthreads();                       // publish write buffer
    };

    #pragma unroll 1
    for (int t2 = 0; t2 < TST / 2; ++t2) {
        const int t = t2 * 2;
        float xA = 0.0f, xB = 0.0f;
        if (wv == 12) {                        // both prefetches issue early
            xA = xb[t + 1];
            xB = xb[(t + 2 < TST) ? (t + 2) : (TST - 1)];
        }
        step1(0,   HSZ, xA);                   // even step: read buf0, write buf1
        step1(HSZ, 0,   xB);                   // odd  step: read buf1, write buf0
    }

    // ---- epilogue: final h in buf 0 (t=255 wrote buf0)
    if (tid < MB) {
        float s = b_lin[0];
        #pragma unroll 10
        for (int k = 0; k < 50; ++k) {
            float hk = (float)(*(const _Float16*)&Hh[tid * HR + k]);
            s += hk * W_lin[k];
        }
        out[bbase + tid] = s;
    }
}

extern "C" void kernel_launch(void* const* d_in, const int* in_sizes, int n_in,
                              void* d_out, int out_size, void* d_ws, size_t ws_size,
                              hipStream_t stream) {
    const float* x     = (const float*)d_in[0];
    const float* W_ih  = (const float*)d_in[1];
    const float* W_hh  = (const float*)d_in[2];
    const float* b_ih  = (const float*)d_in[3];
    const float* b_hh  = (const float*)d_in[4];
    const float* W_lin = (const float*)d_in[5];
    const float* b_lin = (const float*)d_in[6];
    float* out = (float*)d_out;

    lstm_mfma<<<dim3(NBLK), dim3(NTH), 0, stream>>>(
        x, W_ih, W_hh, b_ih, b_hh, W_lin, b_lin, out);
}